// Round 4
// baseline (227.831 us; speedup 1.0000x reference)
//
#include <hip/hip_runtime.h>

// Problem constants (fixed by the reference)
#define BATCH 256
#define CDIM  2048
#define HW    49
#define KDIM  16

// ---------------------------------------------------------------------------
// Kernel A: partial P[hw][k] over a 512-wide C chunk.
// grid = BATCH*4, block = 256 (4 waves); wave wv owns a 128-c sub-slice.
// Main loop is LDS-free: fm via coalesced global_load (vmcnt only, lane=hw),
// w via uniform s_load_dwordx4 (lgkmcnt holds ONLY smem -> cheap drains).
// Lanes 49..63 are masked out of the loop (results were discarded anyway).
// ---------------------------------------------------------------------------
__global__ __launch_bounds__(256) void pconv_kernel(
    const float* __restrict__ fm, const float* __restrict__ w16,
    float* __restrict__ Ppart)
{
    __shared__ __align__(16) float red[4 * 784];   // 12.5 KB, reduce only

    const int tid  = threadIdx.x;
    const int lane = tid & 63;
    const int wv   = __builtin_amdgcn_readfirstlane(tid >> 6);  // 0..3 uniform
    const int b    = blockIdx.x >> 2;
    const int q    = blockIdx.x & 3;

    float acc[16];
    #pragma unroll
    for (int k = 0; k < 16; ++k) acc[k] = 0.f;

    if (lane < HW) {
        const float* fmb = fm + (size_t)b * CDIM * HW + lane;
        const int cbase = q * 512 + wv * 128;
        #pragma unroll 2
        for (int c4 = 0; c4 < 128; c4 += 4) {
            const int cg = cbase + c4;
            // 4 coalesced global loads (196B per wave each), batched on vmcnt
            float f0 = fmb[(cg + 0) * HW];
            float f1 = fmb[(cg + 1) * HW];
            float f2 = fmb[(cg + 2) * HW];
            float f3 = fmb[(cg + 3) * HW];
            // 16 uniform 16B scalar loads (K$/L2-hot, 64B line serves 4 groups)
            #pragma unroll
            for (int k = 0; k < 16; ++k) {
                const float4 wq = *(const float4*)(w16 + k * CDIM + cg);
                acc[k] += wq.x * f0 + wq.y * f1 + wq.z * f2 + wq.w * f3;
            }
        }
    }

    // --- cross-wave reduce via LDS; layout red[wv][hw*16+k] ---
    if (lane < HW) {
        #pragma unroll
        for (int k4 = 0; k4 < 4; ++k4) {
            float4 v;
            v.x = acc[k4 * 4 + 0]; v.y = acc[k4 * 4 + 1];
            v.z = acc[k4 * 4 + 2]; v.w = acc[k4 * 4 + 3];
            *(float4*)&red[wv * 784 + lane * 16 + k4 * 4] = v;
        }
    }
    __syncthreads();
    if (tid < 196) {
        const int e = tid * 4;
        float4 a0 = *(const float4*)&red[e];
        float4 a1 = *(const float4*)&red[784 + e];
        float4 a2 = *(const float4*)&red[1568 + e];
        float4 a3 = *(const float4*)&red[2352 + e];
        float4 o;
        o.x = a0.x + a1.x + a2.x + a3.x;
        o.y = a0.y + a1.y + a2.y + a3.y;
        o.z = a0.z + a1.z + a2.z + a3.z;
        o.w = a0.w + a1.w + a2.w + a3.w;
        *(float4*)(Ppart + (size_t)blockIdx.x * 784 + e) = o;
    }
}

// ---------------------------------------------------------------------------
// Kernel A2: Pbn[b][hw*16+k] = BN(sum of 4 chunk-partials) / 49
// grid = BATCH, block = 256. Tiny; Ppart is L2/L3-resident.
// ---------------------------------------------------------------------------
__global__ __launch_bounds__(256) void preduce_kernel(
    const float* __restrict__ Ppart,
    const float* __restrict__ gamma, const float* __restrict__ beta,
    const float* __restrict__ mean, const float* __restrict__ var,
    float* __restrict__ Pbn)
{
    const int b = blockIdx.x;
    const float* pp = Ppart + (size_t)b * 4 * 784;
    for (int p = threadIdx.x; p < 784; p += 256) {
        float s = pp[p] + pp[p + 784] + pp[p + 1568] + pp[p + 2352];
        const int kk = p & 15;
        float inv   = gamma[kk] * rsqrtf(var[kk] + 1e-5f);
        float shift = beta[kk] - mean[kk] * inv;
        Pbn[(size_t)b * 784 + p] = (s * inv + shift) * (1.0f / 49.0f);
    }
}

// ---------------------------------------------------------------------------
// Kernel B: out[b][k][c] = sum_hw Pbn[b][hw][k] * fm[b][c][hw]
// grid = BATCH*8, block = 256. Thread t owns c = (blockIdx&7)*256 + t.
// Phase 1: stage fm slice to LDS (coalesced b128).
// Phase 2: preload the thread's whole 49-float row into registers
//          (pure-DS, one drain), THEN a fully-unrolled hw loop touching
//          only SMEM (uniform s_loadx4 of Pbn) + FMAs. No DS/SMEM mixing.
// ---------------------------------------------------------------------------
__global__ __launch_bounds__(256) void bp_kernel(
    const float* __restrict__ fm, const float* __restrict__ Pbn,
    float* __restrict__ out)
{
    __shared__ __align__(16) float fm_s[256 * HW];   // 50176 B

    const int tid = threadIdx.x;
    const int b   = blockIdx.x >> 3;
    const int c0  = (blockIdx.x & 7) * 256;

    // stage fm slice: 3136 float4, fully coalesced + contiguous
    const float4* src = (const float4*)(fm + ((size_t)b * CDIM + c0) * HW);
    float4* dst = (float4*)fm_s;
    #pragma unroll
    for (int i = 0; i < 12; ++i) dst[i * 256 + tid] = src[i * 256 + tid];
    if (tid < 64) dst[3072 + tid] = src[3072 + tid];
    __syncthreads();

    // preload this thread's row into registers (stride-49: 2-way bank, free)
    float f[HW];
    #pragma unroll
    for (int i = 0; i < HW; ++i) f[i] = fm_s[tid * HW + i];

    const float* Pb = Pbn + (size_t)b * 784;   // uniform base -> s_load

    float acc[16];
    #pragma unroll
    for (int i = 0; i < 16; ++i) acc[i] = 0.f;

    #pragma unroll
    for (int hw = 0; hw < HW; ++hw) {
        const float4 p0 = *(const float4*)(Pb + hw * 16 + 0);
        const float4 p1 = *(const float4*)(Pb + hw * 16 + 4);
        const float4 p2 = *(const float4*)(Pb + hw * 16 + 8);
        const float4 p3 = *(const float4*)(Pb + hw * 16 + 12);
        const float fv = f[hw];
        acc[0]  += p0.x * fv; acc[1]  += p0.y * fv; acc[2]  += p0.z * fv; acc[3]  += p0.w * fv;
        acc[4]  += p1.x * fv; acc[5]  += p1.y * fv; acc[6]  += p1.z * fv; acc[7]  += p1.w * fv;
        acc[8]  += p2.x * fv; acc[9]  += p2.y * fv; acc[10] += p2.z * fv; acc[11] += p2.w * fv;
        acc[12] += p3.x * fv; acc[13] += p3.y * fv; acc[14] += p3.z * fv; acc[15] += p3.w * fv;
    }

    float* ob = out + (size_t)b * (KDIM * CDIM) + c0 + tid;
    #pragma unroll
    for (int kk = 0; kk < 16; ++kk) ob[kk * CDIM] = acc[kk];
}

extern "C" void kernel_launch(void* const* d_in, const int* in_sizes, int n_in,
                              void* d_out, int out_size, void* d_ws, size_t ws_size,
                              hipStream_t stream) {
    const float* fm    = (const float*)d_in[0];
    const float* w16   = (const float*)d_in[1];
    const float* gamma = (const float*)d_in[2];
    const float* beta  = (const float*)d_in[3];
    const float* mean  = (const float*)d_in[4];
    const float* var   = (const float*)d_in[5];
    float* out   = (float*)d_out;
    float* Ppart = (float*)d_ws;                    // 1024*784*4 = 3.2 MB
    float* Pbn   = Ppart + (size_t)1024 * 784;      // + 256*784*4 = 0.8 MB

    pconv_kernel<<<BATCH * 4, 256, 0, stream>>>(fm, w16, Ppart);
    preduce_kernel<<<BATCH, 256, 0, stream>>>(Ppart, gamma, beta, mean, var, Pbn);
    bp_kernel<<<BATCH * 8, 256, 0, stream>>>(fm, Pbn, out);
}

// Round 5
// 219.035 us; speedup vs baseline: 1.0402x; 1.0402x over previous
//
#include <hip/hip_runtime.h>

// Problem constants (fixed by the reference)
#define BATCH 256
#define CDIM  2048
#define HW    49
#define KDIM  16

__device__ __forceinline__ float rl(float v, int l) {
    return __int_as_float(__builtin_amdgcn_readlane(__float_as_int(v), l));
}

// ---------------------------------------------------------------------------
// Kernel A: partial P[hw][k] over a 512-wide C chunk.
// grid = BATCH*4, block = 256 (4 waves); wave wv owns a 128-c slice.
// w is broadcast from VGPRs via v_readlane (constant lane index) -> the hot
// loop contains ONLY coalesced global loads (vmcnt) + VALU. No LDS, no SMEM.
// ---------------------------------------------------------------------------
__global__ __launch_bounds__(256) void pconv_kernel(
    const float* __restrict__ fm, const float* __restrict__ w16,
    float* __restrict__ Ppart)
{
    __shared__ __align__(16) float red[4 * 784];   // 12.5 KB, reduce only

    const int tid  = threadIdx.x;
    const int lane = tid & 63;
    const int wv   = __builtin_amdgcn_readfirstlane(tid >> 6);  // 0..3 uniform
    const int b    = blockIdx.x >> 2;
    const int q    = blockIdx.x & 3;
    const int cbase = q * 512 + wv * 128;

    const int kw = lane & 15;          // w-preload: which k this lane carries
    const int sw = lane >> 4;          // and which c-sub (0..3)
    const int lrow = (lane < HW) ? lane : (HW - 1);   // clamp: no OOB, no divergence
    const float* fmb = fm + (size_t)b * CDIM * HW + lrow;

    float acc[16];
    #pragma unroll
    for (int k = 0; k < 16; ++k) acc[k] = 0.f;

    #pragma unroll 1
    for (int j2 = 0; j2 < 2; ++j2) {            // two 64-c groups per wave
        const int cg0 = cbase + j2 * 64;
        // preload w group: lane (sw*16+kw) holds w[kw][cg0 + jj*4 + sw]
        float wreg[16];
        {
            const float* wp = w16 + kw * CDIM + cg0 + sw;
            #pragma unroll
            for (int jj = 0; jj < 16; ++jj) wreg[jj] = wp[jj * 4];
        }
        const float* fmc = fmb + (size_t)cg0 * HW;
        #pragma unroll
        for (int jj = 0; jj < 16; ++jj) {
            float f0 = fmc[(jj * 4 + 0) * HW];
            float f1 = fmc[(jj * 4 + 1) * HW];
            float f2 = fmc[(jj * 4 + 2) * HW];
            float f3 = fmc[(jj * 4 + 3) * HW];
            const float wsrc = wreg[jj];
            #pragma unroll
            for (int k = 0; k < 16; ++k) {
                acc[k] += rl(wsrc, k)      * f0
                        + rl(wsrc, 16 + k) * f1
                        + rl(wsrc, 32 + k) * f2
                        + rl(wsrc, 48 + k) * f3;
            }
        }
    }

    // --- cross-wave reduce via LDS; layout red[wv][hw*16+k] ---
    if (lane < HW) {
        #pragma unroll
        for (int k4 = 0; k4 < 4; ++k4) {
            float4 v;
            v.x = acc[k4 * 4 + 0]; v.y = acc[k4 * 4 + 1];
            v.z = acc[k4 * 4 + 2]; v.w = acc[k4 * 4 + 3];
            *(float4*)&red[wv * 784 + lane * 16 + k4 * 4] = v;
        }
    }
    __syncthreads();
    if (tid < 196) {
        const int e = tid * 4;
        float4 a0 = *(const float4*)&red[e];
        float4 a1 = *(const float4*)&red[784 + e];
        float4 a2 = *(const float4*)&red[1568 + e];
        float4 a3 = *(const float4*)&red[2352 + e];
        float4 o;
        o.x = a0.x + a1.x + a2.x + a3.x;
        o.y = a0.y + a1.y + a2.y + a3.y;
        o.z = a0.z + a1.z + a2.z + a3.z;
        o.w = a0.w + a1.w + a2.w + a3.w;
        *(float4*)(Ppart + (size_t)blockIdx.x * 784 + e) = o;
    }
}

// ---------------------------------------------------------------------------
// Kernel A2: Pbn[b][hw*16+k] = BN(sum of 4 chunk-partials) / 49
// grid = BATCH, block = 256. Tiny; Ppart is L2/L3-resident.
// ---------------------------------------------------------------------------
__global__ __launch_bounds__(256) void preduce_kernel(
    const float* __restrict__ Ppart,
    const float* __restrict__ gamma, const float* __restrict__ beta,
    const float* __restrict__ mean, const float* __restrict__ var,
    float* __restrict__ Pbn)
{
    const int b = blockIdx.x;
    const float* pp = Ppart + (size_t)b * 4 * 784;
    for (int p = threadIdx.x; p < 784; p += 256) {
        float s = pp[p] + pp[p + 784] + pp[p + 1568] + pp[p + 2352];
        const int kk = p & 15;
        float inv   = gamma[kk] * rsqrtf(var[kk] + 1e-5f);
        float shift = beta[kk] - mean[kk] * inv;
        Pbn[(size_t)b * 784 + p] = (s * inv + shift) * (1.0f / 49.0f);
    }
}

// ---------------------------------------------------------------------------
// Kernel B: out[b][k][c] = sum_hw Pbn[b][hw][k] * fm[b][c][hw]
// grid = BATCH*8, block = 256. Thread t owns c = (blockIdx&7)*256 + t.
// P broadcast from VGPRs via v_readlane; fm through LDS (coalesced b128 in,
// conflict-free stride-49 b32 out). Hot loop: DS + VALU only.
// ---------------------------------------------------------------------------
__global__ __launch_bounds__(256) void bp_kernel(
    const float* __restrict__ fm, const float* __restrict__ Pbn,
    float* __restrict__ out)
{
    __shared__ __align__(16) float fm_s[256 * HW];   // 50176 B

    const int tid  = threadIdx.x;
    const int lane = tid & 63;
    const int b    = blockIdx.x >> 3;
    const int c0   = (blockIdx.x & 7) * 256;

    // per-lane copy of Pbn slice: preg[j] holds Pb[j*64 + lane]
    const float* Pb = Pbn + (size_t)b * 784;
    float preg[13];
    #pragma unroll
    for (int j = 0; j < 12; ++j) preg[j] = Pb[j * 64 + lane];
    preg[12] = Pb[768 + (lane & 15)];

    // stage fm slice: 3136 float4, fully coalesced + contiguous
    const float4* src = (const float4*)(fm + ((size_t)b * CDIM + c0) * HW);
    float4* dst = (float4*)fm_s;
    #pragma unroll
    for (int i = 0; i < 12; ++i) dst[i * 256 + tid] = src[i * 256 + tid];
    if (tid < 64) dst[3072 + tid] = src[3072 + tid];
    __syncthreads();

    float acc[16];
    #pragma unroll
    for (int i = 0; i < 16; ++i) acc[i] = 0.f;

    const float* row = fm_s + tid * HW;   // stride 49 (17 mod 32): conflict-free
    #pragma unroll
    for (int hw = 0; hw < HW; ++hw) {
        const float f = row[hw];
        #pragma unroll
        for (int k = 0; k < 16; ++k) {
            const int p = hw * 16 + k;          // compile-time constant
            acc[k] += rl(preg[p >> 6], p & 63) * f;
        }
    }

    float* ob = out + (size_t)b * (KDIM * CDIM) + c0 + tid;
    #pragma unroll
    for (int kk = 0; kk < 16; ++kk) ob[kk * CDIM] = acc[kk];
}

extern "C" void kernel_launch(void* const* d_in, const int* in_sizes, int n_in,
                              void* d_out, int out_size, void* d_ws, size_t ws_size,
                              hipStream_t stream) {
    const float* fm    = (const float*)d_in[0];
    const float* w16   = (const float*)d_in[1];
    const float* gamma = (const float*)d_in[2];
    const float* beta  = (const float*)d_in[3];
    const float* mean  = (const float*)d_in[4];
    const float* var   = (const float*)d_in[5];
    float* out   = (float*)d_out;
    float* Ppart = (float*)d_ws;                    // 1024*784*4 = 3.2 MB
    float* Pbn   = Ppart + (size_t)1024 * 784;      // + 256*784*4 = 0.8 MB

    pconv_kernel<<<BATCH * 4, 256, 0, stream>>>(fm, w16, Ppart);
    preduce_kernel<<<BATCH, 256, 0, stream>>>(Ppart, gamma, beta, mean, var, Pbn);
    bp_kernel<<<BATCH * 8, 256, 0, stream>>>(fm, Pbn, out);
}